// Round 1
// baseline (648.332 us; speedup 1.0000x reference)
//
#include <hip/hip_runtime.h>

typedef __bf16 bf16x8 __attribute__((ext_vector_type(8)));
typedef float  f32x4  __attribute__((ext_vector_type(4)));

#define NH    16
#define SEQ   8192
#define EDIM  64
#define CHK   512
#define WCOLS 15872      // 512 + 15*1024
#define OUT0  8388608    // NH*SEQ*EDIM

#define MFMA(a, b, c) __builtin_amdgcn_mfma_f32_16x16x32_bf16((a), (b), (c), 0, 0, 0)

__global__ __launch_bounds__(512) void chunked_attn_kernel(
    const float* __restrict__ Qg, const float* __restrict__ Kg,
    const float* __restrict__ Vg, float* __restrict__ out)
{
    // K frags: idx = ((t*2+es)*4 + quad)*16 + l16, 8 bf16 each -> 64 KB
    __shared__ __align__(16) __bf16 lds_k[32768];
    // V^T frags: idx = ((st*4+nt)*4 + quad)*16 + l16 -> 64 KB
    __shared__ __align__(16) __bf16 lds_v[32768];
    // per-wave P transpose buffer, 16 rows x stride 40 (pad kills bank conflicts)
    __shared__ __align__(16) __bf16 lds_p[8][640];

    const int tid  = threadIdx.x;
    const int lane = tid & 63;
    const int wv   = tid >> 6;      // 0..7
    const int l16  = lane & 15;
    const int quad = lane >> 4;     // 0..3

    const int h  = blockIdx.x >> 4;
    const int n  = blockIdx.x & 15;
    const int ns = (n == 0) ? 0 : n - 1;   // source chunk for K/V

    const size_t qbase = ((size_t)h * SEQ + (size_t)n  * CHK) * EDIM;
    const size_t kbase = ((size_t)h * SEQ + (size_t)ns * CHK) * EDIM;
    float* __restrict__ W = out + OUT0;
    const size_t wrow0  = (size_t)h * CHK;
    const int    colbase = (n == 0) ? 0 : (CHK + (n - 1) * 2 * CHK);

    // ---- zero-fill the masked second half of this chunk's weight window ----
    if (n != 0) {
        const size_t z0 = wrow0 * WCOLS + (size_t)(colbase + CHK);
        #pragma unroll 4
        for (int idx = tid; idx < 512 * 128; idx += 512) {
            const int r = idx >> 7, j = idx & 127;
            f32x4 z = {0.f, 0.f, 0.f, 0.f};
            *(f32x4*)(W + z0 + (size_t)r * WCOLS + (size_t)(j * 4)) = z;
        }
    }

    // ---- stage K as bf16 in MFMA-B frag-major layout ----
    #pragma unroll
    for (int it = 0; it < 8; ++it) {
        const int c = tid + it * 512;          // 4096 chunks of 8 elems
        const int s = c >> 3, sub = c & 7;     // sub = es*4 + qd, e0 = sub*8
        const float* src = Kg + kbase + (size_t)s * EDIM + sub * 8;
        const float4 a = *(const float4*)src;
        const float4 b = *(const float4*)(src + 4);
        bf16x8 t;
        t[0] = (__bf16)a.x; t[1] = (__bf16)a.y; t[2] = (__bf16)a.z; t[3] = (__bf16)a.w;
        t[4] = (__bf16)b.x; t[5] = (__bf16)b.y; t[6] = (__bf16)b.z; t[7] = (__bf16)b.w;
        const int idx = ((s >> 4) * 8 + sub) * 16 + (s & 15);
        ((bf16x8*)lds_k)[idx] = t;
    }

    // ---- stage V^T as bf16 frags (coalesced reads along e) ----
    #pragma unroll
    for (int it = 0; it < 8; ++it) {
        const int c = tid + it * 512;
        const int e = c & 63, sb = c >> 6;     // sb = st*4 + qd, s0 = sb*8
        bf16x8 t;
        #pragma unroll
        for (int j = 0; j < 8; ++j)
            t[j] = (__bf16)Vg[kbase + (size_t)(sb * 8 + j) * EDIM + e];
        const int idx = (((sb >> 2) * 4 + (e >> 4)) * 4 + (sb & 3)) * 16 + (e & 15);
        ((bf16x8*)lds_v)[idx] = t;
    }

    __syncthreads();

    const float SC = 0.125f * 1.44269504088896340736f;  // scale * log2(e), folded into Q
    __bf16* const pb = lds_p[wv];
    const bf16x8* const kf = (const bf16x8*)lds_k;
    const bf16x8* const vf = (const bf16x8*)lds_v;

    for (int mt = 0; mt < 4; ++mt) {
        const int m0 = wv * 64 + mt * 16;      // this wave's m-tile base row
        const int rq = m0 + quad * 4;          // C-layout row base for this lane

        // ---- Q A-frags (scaled, bf16) ----
        bf16x8 aq0, aq1;
        {
            const float* qp = Qg + qbase + (size_t)(m0 + l16) * EDIM + quad * 8;
            float4 a = *(const float4*)(qp);
            float4 b = *(const float4*)(qp + 4);
            aq0[0]=(__bf16)(a.x*SC); aq0[1]=(__bf16)(a.y*SC); aq0[2]=(__bf16)(a.z*SC); aq0[3]=(__bf16)(a.w*SC);
            aq0[4]=(__bf16)(b.x*SC); aq0[5]=(__bf16)(b.y*SC); aq0[6]=(__bf16)(b.z*SC); aq0[7]=(__bf16)(b.w*SC);
            a = *(const float4*)(qp + 32);
            b = *(const float4*)(qp + 36);
            aq1[0]=(__bf16)(a.x*SC); aq1[1]=(__bf16)(a.y*SC); aq1[2]=(__bf16)(a.z*SC); aq1[3]=(__bf16)(a.w*SC);
            aq1[4]=(__bf16)(b.x*SC); aq1[5]=(__bf16)(b.y*SC); aq1[6]=(__bf16)(b.z*SC); aq1[7]=(__bf16)(b.w*SC);
        }

        // ---- pass 1: online row stats (max in log2 domain, sum of exp2) ----
        float mr[4] = {-3.0e38f, -3.0e38f, -3.0e38f, -3.0e38f};
        float lr[4] = {0.f, 0.f, 0.f, 0.f};
        for (int t = 0; t < 32; ++t) {
            const int kb = t * 128 + quad * 16 + l16;
            f32x4 acc = {0.f, 0.f, 0.f, 0.f};
            acc = MFMA(aq0, kf[kb],      acc);
            acc = MFMA(aq1, kf[kb + 64], acc);
            const int col = t * 16 + l16;
            #pragma unroll
            for (int r = 0; r < 4; ++r) {
                const bool  keep = col <= rq + r;
                const float s  = acc[r];
                const float nm = keep ? fmaxf(mr[r], s) : mr[r];
                lr[r] = lr[r] * __builtin_amdgcn_exp2f(mr[r] - nm)
                      + (keep ? __builtin_amdgcn_exp2f(s - nm) : 0.f);
                mr[r] = nm;
            }
        }

        // ---- merge the 16 lanes that share each row ----
        float ri[4];
        #pragma unroll
        for (int r = 0; r < 4; ++r) {
            #pragma unroll
            for (int off = 1; off < 16; off <<= 1) {
                const float mo = __shfl_xor(mr[r], off);
                const float lo = __shfl_xor(lr[r], off);
                const float nm = fmaxf(mr[r], mo);
                lr[r] = lr[r] * __builtin_amdgcn_exp2f(mr[r] - nm)
                      + lo    * __builtin_amdgcn_exp2f(mo    - nm);
                mr[r] = nm;
            }
            ri[r] = __builtin_amdgcn_rcpf(lr[r]);
        }

        // ---- pass 2: recompute S, write normalized weights, accumulate O ----
        f32x4 o0 = {0,0,0,0}, o1 = {0,0,0,0}, o2 = {0,0,0,0}, o3 = {0,0,0,0};
        const size_t wmt = (wrow0 + (size_t)rq) * WCOLS + colbase;
        for (int pr = 0; pr < 16; ++pr) {
            #pragma unroll
            for (int tt = 0; tt < 2; ++tt) {
                const int t  = pr * 2 + tt;
                const int kb = t * 128 + quad * 16 + l16;
                f32x4 acc = {0.f, 0.f, 0.f, 0.f};
                acc = MFMA(aq0, kf[kb],      acc);
                acc = MFMA(aq1, kf[kb + 64], acc);
                const int col = t * 16 + l16;
                #pragma unroll
                for (int r = 0; r < 4; ++r) {
                    const bool  keep = col <= rq + r;
                    const float p = keep
                        ? __builtin_amdgcn_exp2f(acc[r] - mr[r]) * ri[r] : 0.f;
                    W[wmt + (size_t)r * WCOLS + col] = p;          // f32 weights
                    pb[(quad * 4 + r) * 40 + tt * 16 + l16] = (__bf16)p;
                }
            }
            // C-layout -> A-layout via per-wave LDS (in-wave DS ordering, no barrier)
            const bf16x8 pa = *(const bf16x8*)(pb + l16 * 40 + quad * 8);
            const int vb = pr * 256 + quad * 16 + l16;
            o0 = MFMA(pa, vf[vb      ], o0);
            o1 = MFMA(pa, vf[vb +  64], o1);
            o2 = MFMA(pa, vf[vb + 128], o2);
            o3 = MFMA(pa, vf[vb + 192], o3);
        }

        // ---- write O tile ----
        const size_t ob = qbase + (size_t)rq * EDIM + l16;
        #pragma unroll
        for (int r = 0; r < 4; ++r) {
            out[ob + (size_t)r * EDIM     ] = o0[r];
            out[ob + (size_t)r * EDIM + 16] = o1[r];
            out[ob + (size_t)r * EDIM + 32] = o2[r];
            out[ob + (size_t)r * EDIM + 48] = o3[r];
        }
    }
}

extern "C" void kernel_launch(void* const* d_in, const int* in_sizes, int n_in,
                              void* d_out, int out_size, void* d_ws, size_t ws_size,
                              hipStream_t stream) {
    const float* Q = (const float*)d_in[0];
    const float* K = (const float*)d_in[1];
    const float* V = (const float*)d_in[2];
    float* out = (float*)d_out;
    chunked_attn_kernel<<<dim3(256), dim3(512), 0, stream>>>(Q, K, V, out);
}